// Round 6
// baseline (574.125 us; speedup 1.0000x reference)
//
#include <hip/hip_runtime.h>
#include <hip/hip_fp16.h>

#define FEAT 48
#define CH 12            // float4 chunks per row for f32 arrays (G, out)
#define UC 6             // uint4 chunks per row for fp16 u arrays (96B rows)
#define STEPS 10
constexpr float LAM   = 0.9f;
constexpr float OMLAM = 0.1f;

#define SCB 1024
#define SCE 4

// --- setup kernels -------------------------------------------------------

__global__ void count_kernel(const int* __restrict__ row, const int* __restrict__ col,
                             int* __restrict__ deg, int* __restrict__ cnt,
                             int* __restrict__ slot,
                             const int* __restrict__ mask, int* __restrict__ winner,
                             int E, int M) {
    int e = blockIdx.x * blockDim.x + threadIdx.x;
    if (e < E) {
        atomicAdd(&deg[col[e]], 1);
        slot[e] = atomicAdd(&cnt[row[e]], 1);
    }
    if (e < M) atomicMax(&winner[mask[e]], e);   // numpy last-write-wins
}

__global__ void dinv_kernel(const int* __restrict__ deg, float* __restrict__ dinv, int N) {
    int v = blockIdx.x * blockDim.x + threadIdx.x;
    if (v < N) dinv[v] = (float)(1.0 / sqrt((double)deg[v]));   // deg >= 1
}

__global__ void scan_part(const int* __restrict__ cnt, int* __restrict__ off,
                          int* __restrict__ bsum, int n) {
    __shared__ int part[SCB];
    int tid  = threadIdx.x;
    int base = blockIdx.x * (SCB * SCE) + tid * SCE;
    int v[SCE];
    int s = 0;
    #pragma unroll
    for (int k = 0; k < SCE; ++k) {
        int i = base + k;
        v[k] = (i < n) ? cnt[i] : 0;
        s += v[k];
    }
    part[tid] = s;
    __syncthreads();
    for (int d = 1; d < SCB; d <<= 1) {
        int tv = (tid >= d) ? part[tid - d] : 0;
        __syncthreads();
        part[tid] += tv;
        __syncthreads();
    }
    int run = (tid ? part[tid - 1] : 0);
    #pragma unroll
    for (int k = 0; k < SCE; ++k) {
        int i = base + k;
        if (i < n) off[i] = run;
        run += v[k];
    }
    if (tid == SCB - 1) bsum[blockIdx.x] = part[SCB - 1];
}

__global__ void scan_fixup(int* __restrict__ off, const int* __restrict__ bsum,
                           int nblocks, int n) {
    __shared__ int addv;
    int tid = threadIdx.x;
    if (tid == 0) {
        int s = 0;
        for (int b = 0; b < (int)blockIdx.x; ++b) s += bsum[b];
        addv = s;
        if (blockIdx.x == 0) {
            int tot = 0;
            for (int b = 0; b < nblocks; ++b) tot += bsum[b];
            off[n] = tot;
        }
    }
    __syncthreads();
    if (blockIdx.x == 0) return;
    int base = blockIdx.x * (SCB * SCE) + tid * SCE;
    #pragma unroll
    for (int k = 0; k < SCE; ++k) {
        int i = base + k;
        if (i < n) off[i] += addv;
    }
}

__global__ void fill_kernel(const int* __restrict__ row, const int* __restrict__ col,
                            const int* __restrict__ off, const int* __restrict__ slot,
                            int* __restrict__ csr_col, int E) {
    int e = blockIdx.x * blockDim.x + threadIdx.x;
    if (e < E) csr_col[off[row[e]] + slot[e]] = col[e];
}

// fused: G = winner>=0 ? Y[winner] : Z ; u0 = fp16(dinv * G)  (96B rows)
__global__ void prep_kernel(const float4* __restrict__ Z4, const float4* __restrict__ Y4,
                            const int* __restrict__ winner, const float* __restrict__ dinv,
                            float4* __restrict__ G4, uint2* __restrict__ u0, int N) {
    int t = blockIdx.x * blockDim.x + threadIdx.x;
    if (t >= N * CH) return;
    int r = t / CH, q = t - r * CH;
    int w = winner[r];
    float4 g = (w >= 0) ? Y4[(size_t)w * CH + q] : Z4[t];
    G4[t] = g;
    float d = dinv[r];
    __half2 h0 = __floats2half2_rn(d * g.x, d * g.y);
    __half2 h1 = __floats2half2_rn(d * g.z, d * g.w);
    u0[t] = make_uint2(__builtin_bit_cast(unsigned int, h0),
                       __builtin_bit_cast(unsigned int, h1));
}

// --- diffusion step ------------------------------------------------------
// 6 lanes per row, each owns 8 fp16 features (16B uint4 gather per edge).
// 4-wide unroll: 4 independent 16B gathers (64B) in flight per thread.
#define ACC8(v)                                                                  \
    do {                                                                         \
        float2 f_;                                                               \
        f_ = __half22float2(__builtin_bit_cast(__half2, (v).x)); a0 += f_.x; a1 += f_.y; \
        f_ = __half22float2(__builtin_bit_cast(__half2, (v).y)); a2 += f_.x; a3 += f_.y; \
        f_ = __half22float2(__builtin_bit_cast(__half2, (v).z)); a4 += f_.x; a5 += f_.y; \
        f_ = __half22float2(__builtin_bit_cast(__half2, (v).w)); a6 += f_.x; a7 += f_.y; \
    } while (0)

template<bool LAST>
__global__ void diffuse_kernel(const uint4* __restrict__ up, const uint4* __restrict__ u0,
                               const float* __restrict__ dinv, const float4* __restrict__ G4,
                               const int* __restrict__ off, const int* __restrict__ cols,
                               uint4* __restrict__ uout, float4* __restrict__ xout, int N) {
    int t = blockIdx.x * blockDim.x + threadIdx.x;
    if (t >= N * UC) return;
    int r = t / UC, q = t - r * UC;
    int j0 = off[r], j1 = off[r + 1];
    float a0 = 0.f, a1 = 0.f, a2 = 0.f, a3 = 0.f,
          a4 = 0.f, a5 = 0.f, a6 = 0.f, a7 = 0.f;

    int j = j0;
    for (; j + 4 <= j1; j += 4) {
        int c0 = cols[j], c1 = cols[j + 1], c2 = cols[j + 2], c3 = cols[j + 3];
        uint4 v0 = up[(size_t)c0 * UC + q];
        uint4 v1 = up[(size_t)c1 * UC + q];
        uint4 v2 = up[(size_t)c2 * UC + q];
        uint4 v3 = up[(size_t)c3 * UC + q];
        ACC8(v0); ACC8(v1); ACC8(v2); ACC8(v3);
    }
    if (j < j1) {
        int c0 = cols[j];
        int c1 = (j + 1 < j1) ? cols[j + 1] : c0;
        int c2 = (j + 2 < j1) ? cols[j + 2] : c0;
        uint4 v0 = up[(size_t)c0 * UC + q];
        uint4 v1 = up[(size_t)c1 * UC + q];
        uint4 v2 = up[(size_t)c2 * UC + q];
        ACC8(v0);
        if (j + 1 < j1) ACC8(v1);
        if (j + 2 < j1) ACC8(v2);
    }

    float d = dinv[r];
    if (LAST) {
        float s = LAM * d;
        float4 g0 = G4[(size_t)r * CH + 2 * q];
        float4 g1 = G4[(size_t)r * CH + 2 * q + 1];
        float4 o0, o1;
        o0.x = fmaf(s, a0, OMLAM * g0.x);
        o0.y = fmaf(s, a1, OMLAM * g0.y);
        o0.z = fmaf(s, a2, OMLAM * g0.z);
        o0.w = fmaf(s, a3, OMLAM * g0.w);
        o1.x = fmaf(s, a4, OMLAM * g1.x);
        o1.y = fmaf(s, a5, OMLAM * g1.y);
        o1.z = fmaf(s, a6, OMLAM * g1.z);
        o1.w = fmaf(s, a7, OMLAM * g1.w);
        xout[(size_t)r * CH + 2 * q]     = o0;
        xout[(size_t)r * CH + 2 * q + 1] = o1;
    } else {
        float a = LAM * d * d;
        uint4 z = u0[t];
        float2 b0 = __half22float2(__builtin_bit_cast(__half2, z.x));
        float2 b1 = __half22float2(__builtin_bit_cast(__half2, z.y));
        float2 b2 = __half22float2(__builtin_bit_cast(__half2, z.z));
        float2 b3 = __half22float2(__builtin_bit_cast(__half2, z.w));
        __half2 h0 = __floats2half2_rn(fmaf(a, a0, OMLAM * b0.x), fmaf(a, a1, OMLAM * b0.y));
        __half2 h1 = __floats2half2_rn(fmaf(a, a2, OMLAM * b1.x), fmaf(a, a3, OMLAM * b1.y));
        __half2 h2 = __floats2half2_rn(fmaf(a, a4, OMLAM * b2.x), fmaf(a, a5, OMLAM * b2.y));
        __half2 h3 = __floats2half2_rn(fmaf(a, a6, OMLAM * b3.x), fmaf(a, a7, OMLAM * b3.y));
        uout[t] = make_uint4(__builtin_bit_cast(unsigned int, h0),
                             __builtin_bit_cast(unsigned int, h1),
                             __builtin_bit_cast(unsigned int, h2),
                             __builtin_bit_cast(unsigned int, h3));
    }
}

// --- launch --------------------------------------------------------------

extern "C" void kernel_launch(void* const* d_in, const int* in_sizes, int n_in,
                              void* d_out, int out_size, void* d_ws, size_t ws_size,
                              hipStream_t stream) {
    const float* Z    = (const float*)d_in[0];
    const float* Y    = (const float*)d_in[1];
    const int*   mask = (const int*)d_in[2];
    const int*   ei   = (const int*)d_in[3];

    const int N = in_sizes[0] / FEAT;
    const int M = in_sizes[2];
    const int E = in_sizes[3] / 2;
    const int* row = ei;
    const int* col = ei + E;

    char* ws = (char*)d_ws;
    size_t pos = 0;
    auto alloc = [&](size_t bytes) -> void* {
        void* p = ws + pos;
        pos = (pos + bytes + 255) & ~(size_t)255;
        return p;
    };
    float* G      = (float*)alloc((size_t)N * FEAT * 4);
    uint2* u0     = (uint2*)alloc((size_t)N * CH * 8);
    uint2* ua     = (uint2*)alloc((size_t)N * CH * 8);
    uint2* ub     = (uint2*)alloc((size_t)N * CH * 8);
    int*   deg    = (int*)  alloc((size_t)N * 4);
    float* dinv   = (float*)alloc((size_t)N * 4);
    int*   cnt    = (int*)  alloc((size_t)N * 4);
    int*   off    = (int*)  alloc((size_t)(N + 1) * 4);
    int*   winner = (int*)  alloc((size_t)N * 4);
    int*   slot   = (int*)  alloc((size_t)E * 4);
    int*   csr    = (int*)  alloc((size_t)E * 4);
    int*   bsum   = (int*)  alloc((size_t)1024 * 4);

    hipMemsetAsync(deg,    0,    (size_t)N * 4, stream);
    hipMemsetAsync(cnt,    0,    (size_t)N * 4, stream);
    hipMemsetAsync(winner, 0xFF, (size_t)N * 4, stream);

    const int B = 256;
    count_kernel<<<(E + B - 1) / B, B, 0, stream>>>(row, col, deg, cnt, slot,
                                                    mask, winner, E, M);
    dinv_kernel <<<(N + B - 1) / B, B, 0, stream>>>(deg, dinv, N);

    prep_kernel<<<(N * CH + B - 1) / B, B, 0, stream>>>((const float4*)Z, (const float4*)Y,
                                                        winner, dinv, (float4*)G, u0, N);

    const int scan_nb = (N + SCB * SCE - 1) / (SCB * SCE);
    scan_part <<<scan_nb, SCB, 0, stream>>>(cnt, off, bsum, N);
    scan_fixup<<<scan_nb, SCB, 0, stream>>>(off, bsum, scan_nb, N);

    fill_kernel<<<(E + B - 1) / B, B, 0, stream>>>(row, col, off, slot, csr, E);

    // steps 0..8 fp16 ping-pong, step 9 -> f32 d_out
    const int nt = N * UC;
    const uint4* src = (const uint4*)u0;
    uint4* bufs[2] = { (uint4*)ua, (uint4*)ub };
    for (int it = 0; it < STEPS - 1; ++it) {
        uint4* dst = bufs[it & 1];
        diffuse_kernel<false><<<(nt + B - 1) / B, B, 0, stream>>>(
            src, (const uint4*)u0, dinv, (const float4*)G, off, csr, dst, nullptr, N);
        src = dst;
    }
    diffuse_kernel<true><<<(nt + B - 1) / B, B, 0, stream>>>(
        src, (const uint4*)u0, dinv, (const float4*)G, off, csr, nullptr, (float4*)d_out, N);
}

// Round 7
// 444.378 us; speedup vs baseline: 1.2920x; 1.2920x over previous
//
#include <hip/hip_runtime.h>
#include <hip/hip_fp16.h>

#define FEAT 48
#define CH 12            // 12 lanes per node row, 4 fp16 feats (8B) each; 96B u rows
#define STEPS 10
#define BK 256           // nodes per bucket
#define NBMAX 512        // max buckets (N <= 131072)
#define CAP 5120         // edges capacity per bucket (mean 4096 at E=1.6M; +16 sigma)
constexpr float LAM   = 0.9f;
constexpr float OMLAM = 0.1f;

// --- setup: bucketed histogram + CSR build (no per-edge global atomics) ---

__global__ void init_kernel(int* __restrict__ bcur, int* __restrict__ ccur, int nb) {
    int b = blockIdx.x * blockDim.x + threadIdx.x;
    if (b < nb) { bcur[b] = b * CAP; ccur[b] = b * CAP; }
}

__global__ void winner_kernel(const int* __restrict__ mask, int* __restrict__ winner, int M) {
    int i = blockIdx.x * blockDim.x + threadIdx.x;
    if (i < M) atomicMax(&winner[mask[i]], i);   // numpy last-write-wins
}

// Phase A: scatter (row,col) into row-buckets and col into col-buckets.
// Per-block LDS histograms; one global reservation atomic per block x bucket.
__global__ void bucket_scatter(const int* __restrict__ row, const int* __restrict__ col,
                               int* __restrict__ bcur, int* __restrict__ ccur,
                               int2* __restrict__ bstore, int* __restrict__ cstore,
                               int E, int nb, int nblk) {
    __shared__ int hr[NBMAX], cr[NBMAX], hc[NBMAX], cc[NBMAX];
    int tid = threadIdx.x;
    int ce = (E + nblk - 1) / nblk;
    int s = blockIdx.x * ce;
    int e_end = min(E, s + ce);
    for (int i = tid; i < nb; i += blockDim.x) { hr[i] = 0; hc[i] = 0; }
    __syncthreads();
    for (int i = s + tid; i < e_end; i += blockDim.x) {
        atomicAdd(&hr[row[i] >> 8], 1);
        atomicAdd(&hc[col[i] >> 8], 1);
    }
    __syncthreads();
    for (int i = tid; i < nb; i += blockDim.x) {
        cr[i] = hr[i] ? atomicAdd(&bcur[i], hr[i]) : 0;
        cc[i] = hc[i] ? atomicAdd(&ccur[i], hc[i]) : 0;
    }
    __syncthreads();
    for (int i = s + tid; i < e_end; i += blockDim.x) {
        int r = row[i], c = col[i];
        int pr = atomicAdd(&cr[r >> 8], 1);   // LDS cursor (absolute index)
        bstore[pr] = make_int2(r, c);
        int pc = atomicAdd(&cc[c >> 8], 1);
        cstore[pc] = c;
    }
}

// exclusive prefix over bucket totals; also writes off[N] = E
__global__ void bucket_prefix(const int* __restrict__ bcur, int* __restrict__ bpre,
                              int* __restrict__ off, int nb, int E, int N) {
    __shared__ int sh[NBMAX];
    int tid = threadIdx.x;
    int tot = (tid < nb) ? (bcur[tid] - tid * CAP) : 0;
    sh[tid] = tot;
    __syncthreads();
    for (int d = 1; d < NBMAX; d <<= 1) {
        int v = (tid >= d) ? sh[tid - d] : 0;
        __syncthreads();
        sh[tid] += v;
        __syncthreads();
    }
    if (tid < nb) bpre[tid] = sh[tid] - tot;   // exclusive
    if (tid == 0) off[N] = E;
}

// Phase B: per-bucket CSR finish entirely in LDS (256 fine rows)
__global__ void csr_finish(const int2* __restrict__ bstore, const int* __restrict__ bcur,
                           const int* __restrict__ bpre, int* __restrict__ off,
                           int* __restrict__ csr_col, int N) {
    __shared__ int h[BK], loc[BK], cur[BK];
    int b = blockIdx.x, tid = threadIdx.x;
    int cnt  = bcur[b] - b * CAP;
    int base = bpre[b];
    const int2* src = bstore + (size_t)b * CAP;
    h[tid] = 0;
    __syncthreads();
    for (int i = tid; i < cnt; i += BK) atomicAdd(&h[src[i].x & (BK - 1)], 1);
    __syncthreads();
    int v = h[tid];
    loc[tid] = v;
    __syncthreads();
    for (int d = 1; d < BK; d <<= 1) {
        int t = (tid >= d) ? loc[tid - d] : 0;
        __syncthreads();
        loc[tid] += t;
        __syncthreads();
    }
    int excl = loc[tid] - v;
    int r = b * BK + tid;
    if (r < N) off[r] = base + excl;
    cur[tid] = excl;
    __syncthreads();
    for (int i = tid; i < cnt; i += BK) {
        int2 e = src[i];
        int p = atomicAdd(&cur[e.x & (BK - 1)], 1);   // LDS
        csr_col[base + p] = e.y;
    }
}

// Phase B2: per-bucket in-degree histogram -> dinv (no deg array needed)
__global__ void deg_finish(const int* __restrict__ cstore, const int* __restrict__ ccur,
                           float* __restrict__ dinv, int N) {
    __shared__ int h[BK];
    int b = blockIdx.x, tid = threadIdx.x;
    int cnt = ccur[b] - b * CAP;
    const int* src = cstore + (size_t)b * CAP;
    h[tid] = 0;
    __syncthreads();
    for (int i = tid; i < cnt; i += BK) atomicAdd(&h[src[i] & (BK - 1)], 1);
    __syncthreads();
    int c = b * BK + tid;
    if (c < N) dinv[c] = (float)(1.0 / sqrt((double)h[tid]));   // deg >= 1 guaranteed
}

// fused: G = winner>=0 ? Y[winner] : Z ; u0 = fp16(dinv * G)  (96B rows)
__global__ void prep_kernel(const float4* __restrict__ Z4, const float4* __restrict__ Y4,
                            const int* __restrict__ winner, const float* __restrict__ dinv,
                            float4* __restrict__ G4, uint2* __restrict__ u0, int N) {
    int t = blockIdx.x * blockDim.x + threadIdx.x;
    if (t >= N * CH) return;
    int r = t / CH, q = t - r * CH;
    int w = winner[r];
    float4 g = (w >= 0) ? Y4[(size_t)w * CH + q] : Z4[t];
    G4[t] = g;
    float d = dinv[r];
    __half2 h0 = __floats2half2_rn(d * g.x, d * g.y);
    __half2 h1 = __floats2half2_rn(d * g.z, d * g.w);
    u0[t] = make_uint2(__builtin_bit_cast(unsigned int, h0),
                       __builtin_bit_cast(unsigned int, h1));
}

// --- diffusion step (R5 form: 12 lanes/row, 8B gathers, 4-wide unroll) ----
template<bool LAST>
__global__ void diffuse_kernel(const uint2* __restrict__ up, const uint2* __restrict__ u0,
                               const float* __restrict__ dinv, const float4* __restrict__ G4,
                               const int* __restrict__ off, const int* __restrict__ cols,
                               uint2* __restrict__ uout, float4* __restrict__ xout, int N) {
    int t = blockIdx.x * blockDim.x + threadIdx.x;
    if (t >= N * CH) return;
    int r = t / CH, q = t - r * CH;
    int j0 = off[r], j1 = off[r + 1];
    float ax = 0.f, ay = 0.f, az = 0.f, aw = 0.f;

    int j = j0;
    for (; j + 4 <= j1; j += 4) {
        int c0 = cols[j], c1 = cols[j + 1], c2 = cols[j + 2], c3 = cols[j + 3];
        uint2 v0 = up[(size_t)c0 * CH + q];
        uint2 v1 = up[(size_t)c1 * CH + q];
        uint2 v2 = up[(size_t)c2 * CH + q];
        uint2 v3 = up[(size_t)c3 * CH + q];
        float2 f;
        f = __half22float2(__builtin_bit_cast(__half2, v0.x)); ax += f.x; ay += f.y;
        f = __half22float2(__builtin_bit_cast(__half2, v0.y)); az += f.x; aw += f.y;
        f = __half22float2(__builtin_bit_cast(__half2, v1.x)); ax += f.x; ay += f.y;
        f = __half22float2(__builtin_bit_cast(__half2, v1.y)); az += f.x; aw += f.y;
        f = __half22float2(__builtin_bit_cast(__half2, v2.x)); ax += f.x; ay += f.y;
        f = __half22float2(__builtin_bit_cast(__half2, v2.y)); az += f.x; aw += f.y;
        f = __half22float2(__builtin_bit_cast(__half2, v3.x)); ax += f.x; ay += f.y;
        f = __half22float2(__builtin_bit_cast(__half2, v3.y)); az += f.x; aw += f.y;
    }
    if (j < j1) {
        int c0 = cols[j];
        int c1 = (j + 1 < j1) ? cols[j + 1] : c0;
        int c2 = (j + 2 < j1) ? cols[j + 2] : c0;
        uint2 v0 = up[(size_t)c0 * CH + q];
        uint2 v1 = up[(size_t)c1 * CH + q];
        uint2 v2 = up[(size_t)c2 * CH + q];
        float2 f;
        f = __half22float2(__builtin_bit_cast(__half2, v0.x)); ax += f.x; ay += f.y;
        f = __half22float2(__builtin_bit_cast(__half2, v0.y)); az += f.x; aw += f.y;
        if (j + 1 < j1) {
            f = __half22float2(__builtin_bit_cast(__half2, v1.x)); ax += f.x; ay += f.y;
            f = __half22float2(__builtin_bit_cast(__half2, v1.y)); az += f.x; aw += f.y;
        }
        if (j + 2 < j1) {
            f = __half22float2(__builtin_bit_cast(__half2, v2.x)); ax += f.x; ay += f.y;
            f = __half22float2(__builtin_bit_cast(__half2, v2.y)); az += f.x; aw += f.y;
        }
    }

    float d = dinv[r];
    if (LAST) {
        float4 g = G4[t];
        float4 o;
        float s = LAM * d;
        o.x = fmaf(s, ax, OMLAM * g.x);
        o.y = fmaf(s, ay, OMLAM * g.y);
        o.z = fmaf(s, az, OMLAM * g.z);
        o.w = fmaf(s, aw, OMLAM * g.w);
        xout[t] = o;
    } else {
        float a = LAM * d * d;
        uint2 z = u0[t];
        float2 b0 = __half22float2(__builtin_bit_cast(__half2, z.x));
        float2 b1 = __half22float2(__builtin_bit_cast(__half2, z.y));
        __half2 h0 = __floats2half2_rn(fmaf(a, ax, OMLAM * b0.x),
                                       fmaf(a, ay, OMLAM * b0.y));
        __half2 h1 = __floats2half2_rn(fmaf(a, az, OMLAM * b1.x),
                                       fmaf(a, aw, OMLAM * b1.y));
        uout[t] = make_uint2(__builtin_bit_cast(unsigned int, h0),
                             __builtin_bit_cast(unsigned int, h1));
    }
}

// --- launch --------------------------------------------------------------

extern "C" void kernel_launch(void* const* d_in, const int* in_sizes, int n_in,
                              void* d_out, int out_size, void* d_ws, size_t ws_size,
                              hipStream_t stream) {
    const float* Z    = (const float*)d_in[0];
    const float* Y    = (const float*)d_in[1];
    const int*   mask = (const int*)d_in[2];
    const int*   ei   = (const int*)d_in[3];

    const int N = in_sizes[0] / FEAT;
    const int M = in_sizes[2];
    const int E = in_sizes[3] / 2;
    const int* row = ei;
    const int* col = ei + E;
    const int NB = (N + BK - 1) / BK;   // 391 buckets

    char* ws = (char*)d_ws;
    size_t pos = 0;
    auto alloc = [&](size_t bytes) -> void* {
        void* p = ws + pos;
        pos = (pos + bytes + 255) & ~(size_t)255;
        return p;
    };
    float* G      = (float*)alloc((size_t)N * FEAT * 4);
    uint2* u0     = (uint2*)alloc((size_t)N * CH * 8);
    uint2* ua     = (uint2*)alloc((size_t)N * CH * 8);
    uint2* ub     = (uint2*)alloc((size_t)N * CH * 8);
    float* dinv   = (float*)alloc((size_t)N * 4);
    int*   off    = (int*)  alloc((size_t)(N + 1) * 4);
    int*   winner = (int*)  alloc((size_t)N * 4);
    int*   csr    = (int*)  alloc((size_t)E * 4);
    int2*  bstore = (int2*) alloc((size_t)NB * CAP * 8);
    int*   cstore = (int*)  alloc((size_t)NB * CAP * 4);
    int*   bcur   = (int*)  alloc((size_t)NBMAX * 4);
    int*   ccur   = (int*)  alloc((size_t)NBMAX * 4);
    int*   bpre   = (int*)  alloc((size_t)NBMAX * 4);

    hipMemsetAsync(winner, 0xFF, (size_t)N * 4, stream);

    const int B = 256;
    init_kernel  <<<(NB + B - 1) / B, B, 0, stream>>>(bcur, ccur, NB);
    winner_kernel<<<(M + B - 1) / B, B, 0, stream>>>(mask, winner, M);

    const int SBLK = 256;
    bucket_scatter<<<SBLK, B, 0, stream>>>(row, col, bcur, ccur, bstore, cstore, E, NB, SBLK);
    bucket_prefix <<<1, NBMAX, 0, stream>>>(bcur, bpre, off, NB, E, N);
    csr_finish    <<<NB, BK, 0, stream>>>(bstore, bcur, bpre, off, csr, N);
    deg_finish    <<<NB, BK, 0, stream>>>(cstore, ccur, dinv, N);

    prep_kernel<<<(N * CH + B - 1) / B, B, 0, stream>>>((const float4*)Z, (const float4*)Y,
                                                        winner, dinv, (float4*)G, u0, N);

    // steps 0..8 fp16 ping-pong, step 9 -> f32 d_out
    const int nt = N * CH;
    const uint2* src = u0;
    uint2* bufs[2] = { ua, ub };
    for (int it = 0; it < STEPS - 1; ++it) {
        uint2* dst = bufs[it & 1];
        diffuse_kernel<false><<<(nt + B - 1) / B, B, 0, stream>>>(
            src, u0, dinv, (const float4*)G, off, csr, dst, nullptr, N);
        src = dst;
    }
    diffuse_kernel<true><<<(nt + B - 1) / B, B, 0, stream>>>(
        src, u0, dinv, (const float4*)G, off, csr, nullptr, (float4*)d_out, N);
}

// Round 8
// 427.380 us; speedup vs baseline: 1.3434x; 1.0398x over previous
//
#include <hip/hip_runtime.h>
#include <hip/hip_fp16.h>

#define FEAT 48
#define CH 12            // 12 lanes per node row, 4 fp16 feats (8B) each; 96B u rows
#define STEPS 10
#define BK 256           // nodes per bucket
#define NBMAX 512        // max buckets (N <= 131072)
#define CAP 5120         // edges capacity per bucket (mean 4096 at E=1.6M; +16 sigma)
constexpr float LAM   = 0.9f;
constexpr float OMLAM = 0.1f;

// --- setup: bucketed histogram + CSR build (no per-edge global atomics) ---

// fused: bucket cursor init + numpy last-write-wins winner
__global__ void setup_kernel(int* __restrict__ bcur, int* __restrict__ ccur, int nb,
                             const int* __restrict__ mask, int* __restrict__ winner, int M) {
    int i = blockIdx.x * blockDim.x + threadIdx.x;
    if (i < nb) { bcur[i] = i * CAP; ccur[i] = i * CAP; }
    if (i < M) atomicMax(&winner[mask[i]], i);
}

// Phase A: scatter packed (col<<8 | row_local) into row-buckets and col_local
// bytes into col-buckets. LDS histograms; ~200K global reservation atomics.
__global__ __launch_bounds__(1024)
void bucket_scatter(const int* __restrict__ row, const int* __restrict__ col,
                    int* __restrict__ bcur, int* __restrict__ ccur,
                    unsigned int* __restrict__ bstore, unsigned char* __restrict__ cstore,
                    int E, int nb, int nblk) {
    __shared__ int hr[NBMAX], cr[NBMAX], hc[NBMAX], cc[NBMAX];
    int tid = threadIdx.x;
    int ce = (E + nblk - 1) / nblk;
    int s = blockIdx.x * ce;
    int e_end = min(E, s + ce);
    for (int i = tid; i < nb; i += blockDim.x) { hr[i] = 0; hc[i] = 0; }
    __syncthreads();
    for (int i = s + tid; i < e_end; i += blockDim.x) {
        atomicAdd(&hr[row[i] >> 8], 1);
        atomicAdd(&hc[col[i] >> 8], 1);
    }
    __syncthreads();
    for (int i = tid; i < nb; i += blockDim.x) {
        cr[i] = hr[i] ? atomicAdd(&bcur[i], hr[i]) : 0;
        cc[i] = hc[i] ? atomicAdd(&ccur[i], hc[i]) : 0;
    }
    __syncthreads();
    for (int i = s + tid; i < e_end; i += blockDim.x) {
        int r = row[i], c = col[i];
        int pr = atomicAdd(&cr[r >> 8], 1);   // LDS cursor (absolute index)
        bstore[pr] = ((unsigned int)c << 8) | (unsigned int)(r & (BK - 1));
        int pc = atomicAdd(&cc[c >> 8], 1);
        cstore[pc] = (unsigned char)(c & (BK - 1));
    }
}

// exclusive prefix over bucket totals; also writes off[N] = E
__global__ void bucket_prefix(const int* __restrict__ bcur, int* __restrict__ bpre,
                              int* __restrict__ off, int nb, int E, int N) {
    __shared__ int sh[NBMAX];
    int tid = threadIdx.x;
    int tot = (tid < nb) ? (bcur[tid] - tid * CAP) : 0;
    sh[tid] = tot;
    __syncthreads();
    for (int d = 1; d < NBMAX; d <<= 1) {
        int v = (tid >= d) ? sh[tid - d] : 0;
        __syncthreads();
        sh[tid] += v;
        __syncthreads();
    }
    if (tid < nb) bpre[tid] = sh[tid] - tot;   // exclusive
    if (tid == 0) off[N] = E;
}

// Phase B (fused): per-bucket CSR finish + in-degree -> dinv, all in LDS
__global__ void finish_kernel(const unsigned int* __restrict__ bstore,
                              const int* __restrict__ bcur, const int* __restrict__ bpre,
                              const unsigned char* __restrict__ cstore,
                              const int* __restrict__ ccur,
                              int* __restrict__ off, int* __restrict__ csr_col,
                              float* __restrict__ dinv, int N) {
    __shared__ int h[BK], loc[BK], cur[BK];
    int b = blockIdx.x, tid = threadIdx.x;
    // ---- CSR segment (row-bucket) ----
    int cnt  = bcur[b] - b * CAP;
    int base = bpre[b];
    const unsigned int* src = bstore + (size_t)b * CAP;
    h[tid] = 0;
    __syncthreads();
    for (int i = tid; i < cnt; i += BK) atomicAdd(&h[src[i] & (BK - 1)], 1);
    __syncthreads();
    int v = h[tid];
    loc[tid] = v;
    __syncthreads();
    for (int d = 1; d < BK; d <<= 1) {
        int t = (tid >= d) ? loc[tid - d] : 0;
        __syncthreads();
        loc[tid] += t;
        __syncthreads();
    }
    int excl = loc[tid] - v;
    int r = b * BK + tid;
    if (r < N) off[r] = base + excl;
    cur[tid] = excl;
    __syncthreads();
    for (int i = tid; i < cnt; i += BK) {
        unsigned int e = src[i];
        int p = atomicAdd(&cur[e & (BK - 1)], 1);   // LDS
        csr_col[base + p] = (int)(e >> 8);
    }
    // ---- in-degree (col-bucket) ----
    __syncthreads();
    h[tid] = 0;
    __syncthreads();
    int ccnt = ccur[b] - b * CAP;
    const unsigned char* csrc = cstore + (size_t)b * CAP;
    for (int i = tid; i < ccnt; i += BK) atomicAdd(&h[csrc[i]], 1);
    __syncthreads();
    int c = b * BK + tid;
    if (c < N) dinv[c] = (float)(1.0 / sqrt((double)h[tid]));   // deg >= 1 guaranteed
}

// fused: G = winner>=0 ? Y[winner] : Z ; u0 = fp16(dinv * G)  (96B rows)
__global__ void prep_kernel(const float4* __restrict__ Z4, const float4* __restrict__ Y4,
                            const int* __restrict__ winner, const float* __restrict__ dinv,
                            float4* __restrict__ G4, uint2* __restrict__ u0, int N) {
    int t = blockIdx.x * blockDim.x + threadIdx.x;
    if (t >= N * CH) return;
    int r = t / CH, q = t - r * CH;
    int w = winner[r];
    float4 g = (w >= 0) ? Y4[(size_t)w * CH + q] : Z4[t];
    G4[t] = g;
    float d = dinv[r];
    __half2 h0 = __floats2half2_rn(d * g.x, d * g.y);
    __half2 h1 = __floats2half2_rn(d * g.z, d * g.w);
    u0[t] = make_uint2(__builtin_bit_cast(unsigned int, h0),
                       __builtin_bit_cast(unsigned int, h1));
}

// --- diffusion step (12 lanes/row, 8B gathers, 4-wide unroll) -------------
template<bool LAST>
__global__ void diffuse_kernel(const uint2* __restrict__ up, const uint2* __restrict__ u0,
                               const float* __restrict__ dinv, const float4* __restrict__ G4,
                               const int* __restrict__ off, const int* __restrict__ cols,
                               uint2* __restrict__ uout, float4* __restrict__ xout, int N) {
    int t = blockIdx.x * blockDim.x + threadIdx.x;
    if (t >= N * CH) return;
    int r = t / CH, q = t - r * CH;
    int j0 = off[r], j1 = off[r + 1];
    float ax = 0.f, ay = 0.f, az = 0.f, aw = 0.f;

    int j = j0;
    for (; j + 4 <= j1; j += 4) {
        int c0 = cols[j], c1 = cols[j + 1], c2 = cols[j + 2], c3 = cols[j + 3];
        uint2 v0 = up[(size_t)c0 * CH + q];
        uint2 v1 = up[(size_t)c1 * CH + q];
        uint2 v2 = up[(size_t)c2 * CH + q];
        uint2 v3 = up[(size_t)c3 * CH + q];
        float2 f;
        f = __half22float2(__builtin_bit_cast(__half2, v0.x)); ax += f.x; ay += f.y;
        f = __half22float2(__builtin_bit_cast(__half2, v0.y)); az += f.x; aw += f.y;
        f = __half22float2(__builtin_bit_cast(__half2, v1.x)); ax += f.x; ay += f.y;
        f = __half22float2(__builtin_bit_cast(__half2, v1.y)); az += f.x; aw += f.y;
        f = __half22float2(__builtin_bit_cast(__half2, v2.x)); ax += f.x; ay += f.y;
        f = __half22float2(__builtin_bit_cast(__half2, v2.y)); az += f.x; aw += f.y;
        f = __half22float2(__builtin_bit_cast(__half2, v3.x)); ax += f.x; ay += f.y;
        f = __half22float2(__builtin_bit_cast(__half2, v3.y)); az += f.x; aw += f.y;
    }
    if (j < j1) {
        int c0 = cols[j];
        int c1 = (j + 1 < j1) ? cols[j + 1] : c0;
        int c2 = (j + 2 < j1) ? cols[j + 2] : c0;
        uint2 v0 = up[(size_t)c0 * CH + q];
        uint2 v1 = up[(size_t)c1 * CH + q];
        uint2 v2 = up[(size_t)c2 * CH + q];
        float2 f;
        f = __half22float2(__builtin_bit_cast(__half2, v0.x)); ax += f.x; ay += f.y;
        f = __half22float2(__builtin_bit_cast(__half2, v0.y)); az += f.x; aw += f.y;
        if (j + 1 < j1) {
            f = __half22float2(__builtin_bit_cast(__half2, v1.x)); ax += f.x; ay += f.y;
            f = __half22float2(__builtin_bit_cast(__half2, v1.y)); az += f.x; aw += f.y;
        }
        if (j + 2 < j1) {
            f = __half22float2(__builtin_bit_cast(__half2, v2.x)); ax += f.x; ay += f.y;
            f = __half22float2(__builtin_bit_cast(__half2, v2.y)); az += f.x; aw += f.y;
        }
    }

    float d = dinv[r];
    if (LAST) {
        float4 g = G4[t];
        float4 o;
        float s = LAM * d;
        o.x = fmaf(s, ax, OMLAM * g.x);
        o.y = fmaf(s, ay, OMLAM * g.y);
        o.z = fmaf(s, az, OMLAM * g.z);
        o.w = fmaf(s, aw, OMLAM * g.w);
        xout[t] = o;
    } else {
        float a = LAM * d * d;
        uint2 z = u0[t];
        float2 b0 = __half22float2(__builtin_bit_cast(__half2, z.x));
        float2 b1 = __half22float2(__builtin_bit_cast(__half2, z.y));
        __half2 h0 = __floats2half2_rn(fmaf(a, ax, OMLAM * b0.x),
                                       fmaf(a, ay, OMLAM * b0.y));
        __half2 h1 = __floats2half2_rn(fmaf(a, az, OMLAM * b1.x),
                                       fmaf(a, aw, OMLAM * b1.y));
        uout[t] = make_uint2(__builtin_bit_cast(unsigned int, h0),
                             __builtin_bit_cast(unsigned int, h1));
    }
}

// --- launch --------------------------------------------------------------

extern "C" void kernel_launch(void* const* d_in, const int* in_sizes, int n_in,
                              void* d_out, int out_size, void* d_ws, size_t ws_size,
                              hipStream_t stream) {
    const float* Z    = (const float*)d_in[0];
    const float* Y    = (const float*)d_in[1];
    const int*   mask = (const int*)d_in[2];
    const int*   ei   = (const int*)d_in[3];

    const int N = in_sizes[0] / FEAT;
    const int M = in_sizes[2];
    const int E = in_sizes[3] / 2;
    const int* row = ei;
    const int* col = ei + E;
    const int NB = (N + BK - 1) / BK;   // 391 buckets

    char* ws = (char*)d_ws;
    size_t pos = 0;
    auto alloc = [&](size_t bytes) -> void* {
        void* p = ws + pos;
        pos = (pos + bytes + 255) & ~(size_t)255;
        return p;
    };
    float* G      = (float*)alloc((size_t)N * FEAT * 4);
    uint2* u0     = (uint2*)alloc((size_t)N * CH * 8);
    uint2* ua     = (uint2*)alloc((size_t)N * CH * 8);
    uint2* ub     = (uint2*)alloc((size_t)N * CH * 8);
    float* dinv   = (float*)alloc((size_t)N * 4);
    int*   off    = (int*)  alloc((size_t)(N + 1) * 4);
    int*   winner = (int*)  alloc((size_t)N * 4);
    int*   csr    = (int*)  alloc((size_t)E * 4);
    unsigned int*  bstore = (unsigned int*) alloc((size_t)NB * CAP * 4);
    unsigned char* cstore = (unsigned char*)alloc((size_t)NB * CAP);
    int*   bcur   = (int*)  alloc((size_t)NBMAX * 4);
    int*   ccur   = (int*)  alloc((size_t)NBMAX * 4);
    int*   bpre   = (int*)  alloc((size_t)NBMAX * 4);

    hipMemsetAsync(winner, 0xFF, (size_t)N * 4, stream);

    const int B = 256;
    const int setup_n = max(NB, M);
    setup_kernel<<<(setup_n + B - 1) / B, B, 0, stream>>>(bcur, ccur, NB, mask, winner, M);

    const int SBLK = 256;
    bucket_scatter<<<SBLK, 1024, 0, stream>>>(row, col, bcur, ccur, bstore, cstore, E, NB, SBLK);
    bucket_prefix <<<1, NBMAX, 0, stream>>>(bcur, bpre, off, NB, E, N);
    finish_kernel <<<NB, BK, 0, stream>>>(bstore, bcur, bpre, cstore, ccur,
                                          off, csr, dinv, N);

    prep_kernel<<<(N * CH + B - 1) / B, B, 0, stream>>>((const float4*)Z, (const float4*)Y,
                                                        winner, dinv, (float4*)G, u0, N);

    // steps 0..8 fp16 ping-pong, step 9 -> f32 d_out
    const int nt = N * CH;
    const uint2* src = u0;
    uint2* bufs[2] = { ua, ub };
    for (int it = 0; it < STEPS - 1; ++it) {
        uint2* dst = bufs[it & 1];
        diffuse_kernel<false><<<(nt + B - 1) / B, B, 0, stream>>>(
            src, u0, dinv, (const float4*)G, off, csr, dst, nullptr, N);
        src = dst;
    }
    diffuse_kernel<true><<<(nt + B - 1) / B, B, 0, stream>>>(
        src, u0, dinv, (const float4*)G, off, csr, nullptr, (float4*)d_out, N);
}

// Round 9
// 421.340 us; speedup vs baseline: 1.3626x; 1.0143x over previous
//
#include <hip/hip_runtime.h>
#include <hip/hip_fp16.h>

#define FEAT 48
#define CH 12            // 12 lanes per node row, 4 fp16 feats (8B) each; 96B u rows
#define STEPS 10
#define BK 256           // nodes per bucket
#define NBMAX 512        // max buckets (N <= 131072)
#define CAP 5120         // edges capacity per bucket (mean 4096 at E=1.6M; +16 sigma)
constexpr float LAM   = 0.9f;
constexpr float OMLAM = 0.1f;

// --- setup: bucketed histogram + CSR build (no per-edge global atomics) ---

// fused: bucket cursor init + numpy last-write-wins winner
__global__ void setup_kernel(int* __restrict__ bcur, int* __restrict__ ccur, int nb,
                             const int* __restrict__ mask, int* __restrict__ winner, int M) {
    int i = blockIdx.x * blockDim.x + threadIdx.x;
    if (i < nb) { bcur[i] = i * CAP; ccur[i] = i * CAP; }
    if (i < M) atomicMax(&winner[mask[i]], i);
}

// Phase A: scatter packed (col<<8 | row_local) into row-buckets and col_local
// bytes into col-buckets. LDS histograms; ~200K global reservation atomics.
__global__ __launch_bounds__(1024)
void bucket_scatter(const int* __restrict__ row, const int* __restrict__ col,
                    int* __restrict__ bcur, int* __restrict__ ccur,
                    unsigned int* __restrict__ bstore, unsigned char* __restrict__ cstore,
                    int E, int nb, int nblk) {
    __shared__ int hr[NBMAX], cr[NBMAX], hc[NBMAX], cc[NBMAX];
    int tid = threadIdx.x;
    int ce = (E + nblk - 1) / nblk;
    int s = blockIdx.x * ce;
    int e_end = min(E, s + ce);
    for (int i = tid; i < nb; i += blockDim.x) { hr[i] = 0; hc[i] = 0; }
    __syncthreads();
    for (int i = s + tid; i < e_end; i += blockDim.x) {
        atomicAdd(&hr[row[i] >> 8], 1);
        atomicAdd(&hc[col[i] >> 8], 1);
    }
    __syncthreads();
    for (int i = tid; i < nb; i += blockDim.x) {
        cr[i] = hr[i] ? atomicAdd(&bcur[i], hr[i]) : 0;
        cc[i] = hc[i] ? atomicAdd(&ccur[i], hc[i]) : 0;
    }
    __syncthreads();
    for (int i = s + tid; i < e_end; i += blockDim.x) {
        int r = row[i], c = col[i];
        int pr = atomicAdd(&cr[r >> 8], 1);   // LDS cursor (absolute index)
        bstore[pr] = ((unsigned int)c << 8) | (unsigned int)(r & (BK - 1));
        int pc = atomicAdd(&cc[c >> 8], 1);
        cstore[pc] = (unsigned char)(c & (BK - 1));
    }
}

// exclusive prefix over bucket totals; also writes off[N] = E
__global__ void bucket_prefix(const int* __restrict__ bcur, int* __restrict__ bpre,
                              int* __restrict__ off, int nb, int E, int N) {
    __shared__ int sh[NBMAX];
    int tid = threadIdx.x;
    int tot = (tid < nb) ? (bcur[tid] - tid * CAP) : 0;
    sh[tid] = tot;
    __syncthreads();
    for (int d = 1; d < NBMAX; d <<= 1) {
        int v = (tid >= d) ? sh[tid - d] : 0;
        __syncthreads();
        sh[tid] += v;
        __syncthreads();
    }
    if (tid < nb) bpre[tid] = sh[tid] - tot;   // exclusive
    if (tid == 0) off[N] = E;
}

// Phase B (fused): per-bucket CSR finish + in-degree -> dinv, all in LDS
__global__ void finish_kernel(const unsigned int* __restrict__ bstore,
                              const int* __restrict__ bcur, const int* __restrict__ bpre,
                              const unsigned char* __restrict__ cstore,
                              const int* __restrict__ ccur,
                              int* __restrict__ off, int* __restrict__ csr_col,
                              float* __restrict__ dinv, int N) {
    __shared__ int h[BK], loc[BK], cur[BK];
    int b = blockIdx.x, tid = threadIdx.x;
    // ---- CSR segment (row-bucket) ----
    int cnt  = bcur[b] - b * CAP;
    int base = bpre[b];
    const unsigned int* src = bstore + (size_t)b * CAP;
    h[tid] = 0;
    __syncthreads();
    for (int i = tid; i < cnt; i += BK) atomicAdd(&h[src[i] & (BK - 1)], 1);
    __syncthreads();
    int v = h[tid];
    loc[tid] = v;
    __syncthreads();
    for (int d = 1; d < BK; d <<= 1) {
        int t = (tid >= d) ? loc[tid - d] : 0;
        __syncthreads();
        loc[tid] += t;
        __syncthreads();
    }
    int excl = loc[tid] - v;
    int r = b * BK + tid;
    if (r < N) off[r] = base + excl;
    cur[tid] = excl;
    __syncthreads();
    for (int i = tid; i < cnt; i += BK) {
        unsigned int e = src[i];
        int p = atomicAdd(&cur[e & (BK - 1)], 1);   // LDS
        csr_col[base + p] = (int)(e >> 8);
    }
    // ---- in-degree (col-bucket) ----
    __syncthreads();
    h[tid] = 0;
    __syncthreads();
    int ccnt = ccur[b] - b * CAP;
    const unsigned char* csrc = cstore + (size_t)b * CAP;
    for (int i = tid; i < ccnt; i += BK) atomicAdd(&h[csrc[i]], 1);
    __syncthreads();
    int c = b * BK + tid;
    if (c < N) dinv[c] = (float)(1.0 / sqrt((double)h[tid]));   // deg >= 1 guaranteed
}

// fused: G = winner>=0 ? Y[winner] : Z ; u0 = fp16(dinv * G)  (96B rows)
__global__ void prep_kernel(const float4* __restrict__ Z4, const float4* __restrict__ Y4,
                            const int* __restrict__ winner, const float* __restrict__ dinv,
                            float4* __restrict__ G4, uint2* __restrict__ u0, int N) {
    int t = blockIdx.x * blockDim.x + threadIdx.x;
    if (t >= N * CH) return;
    int r = t / CH, q = t - r * CH;
    int w = winner[r];
    float4 g = (w >= 0) ? Y4[(size_t)w * CH + q] : Z4[t];
    G4[t] = g;
    float d = dinv[r];
    __half2 h0 = __floats2half2_rn(d * g.x, d * g.y);
    __half2 h1 = __floats2half2_rn(d * g.z, d * g.w);
    u0[t] = make_uint2(__builtin_bit_cast(unsigned int, h0),
                       __builtin_bit_cast(unsigned int, h1));
}

// --- diffusion step (12 lanes/row, 8B gathers, 8-wide unroll for MLP) -----
#define ACC4(v)                                                                      \
    do {                                                                             \
        float2 f_;                                                                   \
        f_ = __half22float2(__builtin_bit_cast(__half2, (v).x)); ax += f_.x; ay += f_.y; \
        f_ = __half22float2(__builtin_bit_cast(__half2, (v).y)); az += f_.x; aw += f_.y; \
    } while (0)

template<bool LAST>
__global__ void diffuse_kernel(const uint2* __restrict__ up, const uint2* __restrict__ u0,
                               const float* __restrict__ dinv, const float4* __restrict__ G4,
                               const int* __restrict__ off, const int* __restrict__ cols,
                               uint2* __restrict__ uout, float4* __restrict__ xout, int N) {
    int t = blockIdx.x * blockDim.x + threadIdx.x;
    if (t >= N * CH) return;
    int r = t / CH, q = t - r * CH;
    int j0 = off[r], j1 = off[r + 1];
    float ax = 0.f, ay = 0.f, az = 0.f, aw = 0.f;

    int j = j0;
    for (; j + 8 <= j1; j += 8) {
        int c0 = cols[j],     c1 = cols[j + 1], c2 = cols[j + 2], c3 = cols[j + 3];
        int c4 = cols[j + 4], c5 = cols[j + 5], c6 = cols[j + 6], c7 = cols[j + 7];
        uint2 v0 = up[(size_t)c0 * CH + q];
        uint2 v1 = up[(size_t)c1 * CH + q];
        uint2 v2 = up[(size_t)c2 * CH + q];
        uint2 v3 = up[(size_t)c3 * CH + q];
        uint2 v4 = up[(size_t)c4 * CH + q];
        uint2 v5 = up[(size_t)c5 * CH + q];
        uint2 v6 = up[(size_t)c6 * CH + q];
        uint2 v7 = up[(size_t)c7 * CH + q];
        ACC4(v0); ACC4(v1); ACC4(v2); ACC4(v3);
        ACC4(v4); ACC4(v5); ACC4(v6); ACC4(v7);
    }
    if (j + 4 <= j1) {
        int c0 = cols[j], c1 = cols[j + 1], c2 = cols[j + 2], c3 = cols[j + 3];
        uint2 v0 = up[(size_t)c0 * CH + q];
        uint2 v1 = up[(size_t)c1 * CH + q];
        uint2 v2 = up[(size_t)c2 * CH + q];
        uint2 v3 = up[(size_t)c3 * CH + q];
        ACC4(v0); ACC4(v1); ACC4(v2); ACC4(v3);
        j += 4;
    }
    if (j < j1) {
        int c0 = cols[j];
        int c1 = (j + 1 < j1) ? cols[j + 1] : c0;
        int c2 = (j + 2 < j1) ? cols[j + 2] : c0;
        uint2 v0 = up[(size_t)c0 * CH + q];
        uint2 v1 = up[(size_t)c1 * CH + q];
        uint2 v2 = up[(size_t)c2 * CH + q];
        ACC4(v0);
        if (j + 1 < j1) ACC4(v1);
        if (j + 2 < j1) ACC4(v2);
    }

    float d = dinv[r];
    if (LAST) {
        float4 g = G4[t];
        float4 o;
        float s = LAM * d;
        o.x = fmaf(s, ax, OMLAM * g.x);
        o.y = fmaf(s, ay, OMLAM * g.y);
        o.z = fmaf(s, az, OMLAM * g.z);
        o.w = fmaf(s, aw, OMLAM * g.w);
        xout[t] = o;
    } else {
        float a = LAM * d * d;
        uint2 z = u0[t];
        float2 b0 = __half22float2(__builtin_bit_cast(__half2, z.x));
        float2 b1 = __half22float2(__builtin_bit_cast(__half2, z.y));
        __half2 h0 = __floats2half2_rn(fmaf(a, ax, OMLAM * b0.x),
                                       fmaf(a, ay, OMLAM * b0.y));
        __half2 h1 = __floats2half2_rn(fmaf(a, az, OMLAM * b1.x),
                                       fmaf(a, aw, OMLAM * b1.y));
        uout[t] = make_uint2(__builtin_bit_cast(unsigned int, h0),
                             __builtin_bit_cast(unsigned int, h1));
    }
}

// --- launch --------------------------------------------------------------

extern "C" void kernel_launch(void* const* d_in, const int* in_sizes, int n_in,
                              void* d_out, int out_size, void* d_ws, size_t ws_size,
                              hipStream_t stream) {
    const float* Z    = (const float*)d_in[0];
    const float* Y    = (const float*)d_in[1];
    const int*   mask = (const int*)d_in[2];
    const int*   ei   = (const int*)d_in[3];

    const int N = in_sizes[0] / FEAT;
    const int M = in_sizes[2];
    const int E = in_sizes[3] / 2;
    const int* row = ei;
    const int* col = ei + E;
    const int NB = (N + BK - 1) / BK;   // 391 buckets

    char* ws = (char*)d_ws;
    size_t pos = 0;
    auto alloc = [&](size_t bytes) -> void* {
        void* p = ws + pos;
        pos = (pos + bytes + 255) & ~(size_t)255;
        return p;
    };
    float* G      = (float*)alloc((size_t)N * FEAT * 4);
    uint2* u0     = (uint2*)alloc((size_t)N * CH * 8);
    uint2* ua     = (uint2*)alloc((size_t)N * CH * 8);
    uint2* ub     = (uint2*)alloc((size_t)N * CH * 8);
    float* dinv   = (float*)alloc((size_t)N * 4);
    int*   off    = (int*)  alloc((size_t)(N + 1) * 4);
    int*   winner = (int*)  alloc((size_t)N * 4);
    int*   csr    = (int*)  alloc((size_t)E * 4);
    unsigned int*  bstore = (unsigned int*) alloc((size_t)NB * CAP * 4);
    unsigned char* cstore = (unsigned char*)alloc((size_t)NB * CAP);
    int*   bcur   = (int*)  alloc((size_t)NBMAX * 4);
    int*   ccur   = (int*)  alloc((size_t)NBMAX * 4);
    int*   bpre   = (int*)  alloc((size_t)NBMAX * 4);

    hipMemsetAsync(winner, 0xFF, (size_t)N * 4, stream);

    const int B = 256;
    const int setup_n = max(NB, M);
    setup_kernel<<<(setup_n + B - 1) / B, B, 0, stream>>>(bcur, ccur, NB, mask, winner, M);

    const int SBLK = 256;
    bucket_scatter<<<SBLK, 1024, 0, stream>>>(row, col, bcur, ccur, bstore, cstore, E, NB, SBLK);
    bucket_prefix <<<1, NBMAX, 0, stream>>>(bcur, bpre, off, NB, E, N);
    finish_kernel <<<NB, BK, 0, stream>>>(bstore, bcur, bpre, cstore, ccur,
                                          off, csr, dinv, N);

    prep_kernel<<<(N * CH + B - 1) / B, B, 0, stream>>>((const float4*)Z, (const float4*)Y,
                                                        winner, dinv, (float4*)G, u0, N);

    // steps 0..8 fp16 ping-pong, step 9 -> f32 d_out
    const int nt = N * CH;
    const uint2* src = u0;
    uint2* bufs[2] = { ua, ub };
    for (int it = 0; it < STEPS - 1; ++it) {
        uint2* dst = bufs[it & 1];
        diffuse_kernel<false><<<(nt + B - 1) / B, B, 0, stream>>>(
            src, u0, dinv, (const float4*)G, off, csr, dst, nullptr, N);
        src = dst;
    }
    diffuse_kernel<true><<<(nt + B - 1) / B, B, 0, stream>>>(
        src, u0, dinv, (const float4*)G, off, csr, nullptr, (float4*)d_out, N);
}